// Round 4
// baseline (1340.172 us; speedup 1.0000x reference)
//
#include <hip/hip_runtime.h>

#define Bc 16
#define Tc 16
#define Cc 512
#define Kc 64
#define Sc 196
#define BKS (Bc*Kc*Sc)      // 200704
#define TBKS (Tc*BKS)       // 3211264

#define GPLANE 288                    // 18 rows * 16 cols per plane
#define GP_TOT (16 + 64*GPLANE + 16)  // 18464 floats incl guards

__device__ __forceinline__ float sigmoid_f(float x) { return 1.f / (1.f + __expf(-x)); }
__device__ __forceinline__ float tanh_f(float x) { return 1.f - 2.f / (__expf(2.f * x) + 1.f); }

// ---------------- transpose share_w: wt[c][k] = w[k][c] ----------------
__global__ __launch_bounds__(256) void k_transpose_w(const float* __restrict__ w, float* __restrict__ wt) {
    int idx = blockIdx.x * 256 + threadIdx.x;
    if (idx < Kc * Cc) {
        int k = idx & 63, c = idx >> 6;
        wt[idx] = w[k * Cc + c];
    }
}

// ---------------- conv1x1: 4k x 16s register tiles, VALU-bound inner loop ----------------
// grid 392 (128 gs each), block 128. kq = tid>>3 (k = kq*4+i), sq = tid&7 (cols sq*4+32u+j)
__global__ __launch_bounds__(128) void k_conv1x1(const float* __restrict__ x, const float* __restrict__ wt,
                                                 const float* __restrict__ bias, float* __restrict__ wxb) {
    __shared__ float Ws[32][64];
    __shared__ float Xs[32][128];
    const int tid = threadIdx.x;
    const int gs0 = blockIdx.x * 128;
    const int kq = tid >> 3;
    const int sq = tid & 7;
    // staging column (one col per thread, 32 rows per c0 chunk)
    const int gs_c = gs0 + tid;
    const int n_c = gs_c / Sc, s_c = gs_c - n_c * Sc;
    const float* xcol = x + (size_t)n_c * Cc * Sc + s_c;
    const int wrow = tid >> 2, wcol = (tid & 3) * 16;

    float acc[4][16] = {};
    for (int c0 = 0; c0 < Cc; c0 += 32) {
        __syncthreads();
        {
            const float* wp = wt + (size_t)(c0 + wrow) * Kc + wcol;
            float4 a0 = *(const float4*)wp;
            float4 a1 = *(const float4*)(wp + 4);
            float4 a2 = *(const float4*)(wp + 8);
            float4 a3 = *(const float4*)(wp + 12);
            *(float4*)&Ws[wrow][wcol]      = a0;
            *(float4*)&Ws[wrow][wcol + 4]  = a1;
            *(float4*)&Ws[wrow][wcol + 8]  = a2;
            *(float4*)&Ws[wrow][wcol + 12] = a3;
        }
        {
            const float* xp = xcol + (size_t)c0 * Sc;
#pragma unroll
            for (int r = 0; r < 32; ++r) Xs[r][tid] = xp[(size_t)r * Sc];
        }
        __syncthreads();
#pragma unroll 8
        for (int cc = 0; cc < 32; ++cc) {
            float4 wv = *(const float4*)&Ws[cc][kq * 4];
            float av[4] = {wv.x, wv.y, wv.z, wv.w};
#pragma unroll
            for (int u = 0; u < 4; ++u) {
                float4 xv = *(const float4*)&Xs[cc][sq * 4 + 32 * u];
                float xs[4] = {xv.x, xv.y, xv.z, xv.w};
#pragma unroll
                for (int i = 0; i < 4; ++i)
#pragma unroll
                    for (int j = 0; j < 4; ++j)
                        acc[i][u * 4 + j] += av[i] * xs[j];
            }
        }
    }
    float bv[4];
#pragma unroll
    for (int i = 0; i < 4; ++i) bv[i] = bias[kq * 4 + i];
#pragma unroll
    for (int u = 0; u < 4; ++u) {
        int gs = gs0 + sq * 4 + 32 * u;
        int n = gs / Sc, s = gs - n * Sc;
        int t = n & 15, bb = n >> 4;
#pragma unroll
        for (int j = 0; j < 4; ++j) {
#pragma unroll
            for (int i = 0; i < 4; ++i) {
                int k = kq * 4 + i;
                wxb[(((size_t)t * Bc + bb) * Kc + k) * Sc + s] = acc[i][u * 4 + j] + bv[i];
            }
            if (++s == Sc) { s = 0; ++n; t = n & 15; bb = n >> 4; }
        }
    }
}

// ---------------- persistent GRU: all 16 steps in one cooperative launch ----------------
// grid 256 = (kt*16 + b), block 512. Per-b barrier: 16 blocks, leader release-add + spin + acquire fence.
__global__ __launch_bounds__(512) void k_gru_persist(
        const float* __restrict__ wxb, const float* __restrict__ Uz,
        const float* __restrict__ Ur, const float* __restrict__ Uh,
        float* __restrict__ zb, float* __restrict__ rh,
        float* __restrict__ assign, int* cnt) {
    extern __shared__ float lds[];
    float* P = lds + 16;
    float* red = lds + GP_TOT;
    const int b  = blockIdx.x & 15;
    const int kt = blockIdx.x >> 4;
    const int k0 = kt * 4;
    const int tid = threadIdx.x;
    const int wave = tid >> 6, lane = tid & 63;
    const int kiw = __builtin_amdgcn_readfirstlane(wave << 3);
    const int yp = lane >> 2, xq = (lane & 3) << 2;
    int* mycnt = cnt + b * 16;

    for (int i = tid; i < GP_TOT; i += 512) lds[i] = 0.f;   // pads stay 0 forever

    const float* uz0 = Uz + (size_t)k0 * 576 + (size_t)kiw * 9;
    const float* ur0 = Ur + (size_t)k0 * 576 + (size_t)kiw * 9;
    const float* uh0 = Uh + (size_t)k0 * 576 + (size_t)kiw * 9;
    const float* Pw = P + (size_t)kiw * GPLANE + yp * 16 + xq;
    const size_t bKS = (size_t)b * (Kc * Sc);
    int ph = 0;

    for (int t = 0; t < Tc; ++t) {
        const float* wxb_t = wxb + (size_t)t * BKS;
        // ================= phase A: z, r*h =================
        if (t > 0) {
            const float* hb = assign + (size_t)(t - 1) * BKS + bKS;
            for (int i = tid; i < Kc * Sc; i += 512) {
                int kk = i / Sc, s = i - kk * Sc;
                int y = s / 14, xx = s - y * 14;
                P[kk * GPLANE + (y + 2) * 16 + xx + 1] = hb[i];
            }
        }
        __syncthreads();
        {
            float az[4][4] = {}, ar[4][4] = {};
#pragma unroll 2
            for (int ki = 0; ki < 8; ++ki) {
                const float* pk = Pw + ki * GPLANE;
#pragma unroll
                for (int dy = 0; dy < 3; ++dy) {
                    const float* row = pk + dy * 16;
                    float4 m = *(const float4*)row;
                    float e0 = row[-1], e4 = row[4];
#pragma unroll
                    for (int r = 0; r < 4; ++r) {
                        const float* wz = uz0 + r * 576 + ki * 9 + dy * 3;
                        float c0 = wz[0], c1 = wz[1], c2 = wz[2];
                        az[r][0] += c0*e0  + c1*m.x + c2*m.y;
                        az[r][1] += c0*m.x + c1*m.y + c2*m.z;
                        az[r][2] += c0*m.y + c1*m.z + c2*m.w;
                        az[r][3] += c0*m.z + c1*m.w + c2*e4;
                        const float* wr = ur0 + r * 576 + ki * 9 + dy * 3;
                        float d0 = wr[0], d1 = wr[1], d2 = wr[2];
                        ar[r][0] += d0*e0  + d1*m.x + d2*m.y;
                        ar[r][1] += d0*m.x + d1*m.y + d2*m.z;
                        ar[r][2] += d0*m.y + d1*m.z + d2*m.w;
                        ar[r][3] += d0*m.z + d1*m.w + d2*e4;
                    }
                }
            }
            float* rp = red + (size_t)wave * 2048 + lane;
#pragma unroll
            for (int r = 0; r < 4; ++r)
#pragma unroll
                for (int j = 0; j < 4; ++j) {
                    rp[(size_t)(r * 8 + j) * 64] = az[r][j];
                    rp[(size_t)(r * 8 + 4 + j) * 64] = ar[r][j];
                }
        }
        __syncthreads();
        {
            const int g = wave >> 2, j = wave & 3;
            const int yq = lane >> 2;
            const int xb = ((lane & 3) << 2) + j;
            float v[4];
#pragma unroll
            for (int r = 0; r < 4; ++r) {
                const int idx = r * 8 + g * 4 + j;
                float s0 = 0.f;
#pragma unroll
                for (int w = 0; w < 8; ++w) s0 += red[(size_t)(w * 32 + idx) * 64 + lane];
                v[r] = s0;
            }
            if (yq >= 1 && yq <= 14 && xb >= 1 && xb <= 14) {
                const int s = (yq - 1) * 14 + (xb - 1);
#pragma unroll
                for (int r = 0; r < 4; ++r) {
                    const size_t base = ((size_t)b * Kc + k0 + r) * Sc + s;
                    float pre = wxb_t[base];
                    if (g == 0) {
                        zb[base] = sigmoid_f(pre + v[r]);
                    } else {
                        float hv = P[(size_t)(k0 + r) * GPLANE + (yq + 1) * 16 + xb];
                        rh[base] = sigmoid_f(pre + v[r]) * hv;
                    }
                }
            }
        }
        __syncthreads();
        ++ph;
        if (tid == 0) {
            __hip_atomic_fetch_add(mycnt, 1, __ATOMIC_RELEASE, __HIP_MEMORY_SCOPE_AGENT);
            while (__hip_atomic_load(mycnt, __ATOMIC_RELAXED, __HIP_MEMORY_SCOPE_AGENT) < 16 * ph)
                __builtin_amdgcn_s_sleep(1);
        }
        __syncthreads();
        __builtin_amdgcn_fence(__ATOMIC_ACQUIRE, "agent");
        // ================= phase B: h_new =================
        {
            const float* hb = rh + bKS;
            for (int i = tid; i < Kc * Sc; i += 512) {
                int kk = i / Sc, s = i - kk * Sc;
                int y = s / 14, xx = s - y * 14;
                P[kk * GPLANE + (y + 2) * 16 + xx + 1] = hb[i];
            }
        }
        __syncthreads();
        {
            float ah[4][4] = {};
#pragma unroll 2
            for (int ki = 0; ki < 8; ++ki) {
                const float* pk = Pw + ki * GPLANE;
#pragma unroll
                for (int dy = 0; dy < 3; ++dy) {
                    const float* row = pk + dy * 16;
                    float4 m = *(const float4*)row;
                    float e0 = row[-1], e4 = row[4];
#pragma unroll
                    for (int r = 0; r < 4; ++r) {
                        const float* wh = uh0 + r * 576 + ki * 9 + dy * 3;
                        float c0 = wh[0], c1 = wh[1], c2 = wh[2];
                        ah[r][0] += c0*e0  + c1*m.x + c2*m.y;
                        ah[r][1] += c0*m.x + c1*m.y + c2*m.z;
                        ah[r][2] += c0*m.y + c1*m.z + c2*m.w;
                        ah[r][3] += c0*m.z + c1*m.w + c2*e4;
                    }
                }
            }
            float* rp = red + (size_t)wave * 1024 + lane;
#pragma unroll
            for (int r = 0; r < 4; ++r)
#pragma unroll
                for (int j = 0; j < 4; ++j)
                    rp[(size_t)(r * 4 + j) * 64] = ah[r][j];
        }
        __syncthreads();
        {
            const int j = wave & 3, rr = wave >> 2;
            const int yq = lane >> 2;
            const int xb = ((lane & 3) << 2) + j;
            float v[2];
#pragma unroll
            for (int m = 0; m < 2; ++m) {
                const int idx = (rr + 2 * m) * 4 + j;
                float s0 = 0.f;
#pragma unroll
                for (int w = 0; w < 8; ++w) s0 += red[(size_t)(w * 16 + idx) * 64 + lane];
                v[m] = s0;
            }
            if (yq >= 1 && yq <= 14 && xb >= 1 && xb <= 14) {
                const int s = (yq - 1) * 14 + (xb - 1);
#pragma unroll
                for (int m = 0; m < 2; ++m) {
                    const int r = rr + 2 * m;
                    const size_t base = ((size_t)b * Kc + k0 + r) * Sc + s;
                    float pre = wxb_t[base];
                    float zv = zb[base];
                    float hp = (t > 0) ? assign[(size_t)(t - 1) * BKS + base] : 0.f;
                    float hh = tanh_f(pre + v[m]);
                    assign[(size_t)t * BKS + base] = (1.f - zv) * hh + zv * hp;
                }
            }
        }
        __syncthreads();
        ++ph;
        if (tid == 0) {
            __hip_atomic_fetch_add(mycnt, 1, __ATOMIC_RELEASE, __HIP_MEMORY_SCOPE_AGENT);
            while (__hip_atomic_load(mycnt, __ATOMIC_RELAXED, __HIP_MEMORY_SCOPE_AGENT) < 16 * ph)
                __builtin_amdgcn_s_sleep(1);
        }
        __syncthreads();
        __builtin_amdgcn_fence(__ATOMIC_ACQUIRE, "agent");
    }
}

// ---------------- asum_tot[b][k] = sum_{t,s} assign ----------------
__global__ __launch_bounds__(64) void k_asum(const float* __restrict__ assign, float* __restrict__ asum) {
    const int bk = blockIdx.x;
    const int b = bk >> 6, k = bk & 63;
    float s = 0.f;
    for (int i = threadIdx.x; i < Tc * Sc; i += 64) {
        int t = i / Sc, sp = i - t * Sc;
        s += assign[(((size_t)t * Bc + b) * Kc + k) * Sc + sp];
    }
#pragma unroll
    for (int o = 1; o < 64; o <<= 1) s += __shfl_xor(s, o);
    if (threadIdx.x == 0) asum[bk] = s;
}

// ---------------- einsum: 512 thr, conflict-free Xs via register transpose, s-half split ----------------
__global__ __launch_bounds__(512) void k_einsum(const float* __restrict__ x, const float* __restrict__ assign,
                                                float* __restrict__ part) {
    extern __shared__ float lds[];
    float* As = lds;                 // [196][68]
    float* Xs = lds + 196 * 68;      // [28][132]
    const int ct = blockIdx.x, tg = blockIdx.y, b = blockIdx.z;
    const int tid = threadIdx.x;
    const int wave = tid >> 6, lane = tid & 63;
    const int kq = wave & 3, sh = wave >> 2;
    const int kh = lane >> 5, c32 = lane & 31;
    const int kbase = kq * 16 + kh * 8;
    float4 acc[8] = {};
    for (int ti = 0; ti < 4; ++ti) {
        const int t = tg * 4 + ti;
        const int n = b * Tc + t;
        __syncthreads();
        {
            const float* ap = assign + ((size_t)t * Bc + b) * (Kc * Sc);
            for (int i = tid; i < Kc * Sc; i += 512) {
                int kk = i / Sc, s = i - kk * Sc;
                As[(size_t)s * 68 + kk] = ap[i];
            }
        }
        for (int sc = 0; sc < 7; ++sc) {
            const int sb = sc * 28;
            __syncthreads();
            if (tid < 224) {
                const int sg = tid >> 5, cgi = tid & 31;
                const float* xp = x + ((size_t)n * Cc + ct * 128 + cgi * 4) * Sc + sb + sg * 4;
                float4 r0 = *(const float4*)xp;
                float4 r1 = *(const float4*)(xp + Sc);
                float4 r2 = *(const float4*)(xp + 2 * Sc);
                float4 r3 = *(const float4*)(xp + 3 * Sc);
                float* xd = Xs + (size_t)(sg * 4) * 132 + cgi * 4;
                *(float4*)(xd)       = make_float4(r0.x, r1.x, r2.x, r3.x);
                *(float4*)(xd + 132) = make_float4(r0.y, r1.y, r2.y, r3.y);
                *(float4*)(xd + 264) = make_float4(r0.z, r1.z, r2.z, r3.z);
                *(float4*)(xd + 396) = make_float4(r0.w, r1.w, r2.w, r3.w);
            }
            __syncthreads();
            const int s0 = sh * 14;
#pragma unroll 2
            for (int si = 0; si < 14; ++si) {
                const int sl = s0 + si;
                const float* ap = As + (size_t)(sb + sl) * 68 + kbase;
                float4 a0 = *(const float4*)ap;
                float4 a1 = *(const float4*)(ap + 4);
                float4 xv = *(const float4*)(Xs + (size_t)sl * 132 + c32 * 4);
                acc[0].x += a0.x * xv.x; acc[0].y += a0.x * xv.y; acc[0].z += a0.x * xv.z; acc[0].w += a0.x * xv.w;
                acc[1].x += a0.y * xv.x; acc[1].y += a0.y * xv.y; acc[1].z += a0.y * xv.z; acc[1].w += a0.y * xv.w;
                acc[2].x += a0.z * xv.x; acc[2].y += a0.z * xv.y; acc[2].z += a0.z * xv.z; acc[2].w += a0.z * xv.w;
                acc[3].x += a0.w * xv.x; acc[3].y += a0.w * xv.y; acc[3].z += a0.w * xv.z; acc[3].w += a0.w * xv.w;
                acc[4].x += a1.x * xv.x; acc[4].y += a1.x * xv.y; acc[4].z += a1.x * xv.z; acc[4].w += a1.x * xv.w;
                acc[5].x += a1.y * xv.x; acc[5].y += a1.y * xv.y; acc[5].z += a1.y * xv.z; acc[5].w += a1.y * xv.w;
                acc[6].x += a1.z * xv.x; acc[6].y += a1.z * xv.y; acc[6].z += a1.z * xv.z; acc[6].w += a1.z * xv.w;
                acc[7].x += a1.w * xv.x; acc[7].y += a1.w * xv.y; acc[7].z += a1.w * xv.z; acc[7].w += a1.w * xv.w;
            }
        }
    }
    __syncthreads();
    if (sh == 1) {
        float* rp = As + (size_t)kq * 2048 + lane;
#pragma unroll
        for (int q = 0; q < 8; ++q) {
            rp[(size_t)(q * 4 + 0) * 64] = acc[q].x;
            rp[(size_t)(q * 4 + 1) * 64] = acc[q].y;
            rp[(size_t)(q * 4 + 2) * 64] = acc[q].z;
            rp[(size_t)(q * 4 + 3) * 64] = acc[q].w;
        }
    }
    __syncthreads();
    if (sh == 0) {
        const float* rp = As + (size_t)kq * 2048 + lane;
#pragma unroll
        for (int q = 0; q < 8; ++q) {
            acc[q].x += rp[(size_t)(q * 4 + 0) * 64];
            acc[q].y += rp[(size_t)(q * 4 + 1) * 64];
            acc[q].z += rp[(size_t)(q * 4 + 2) * 64];
            acc[q].w += rp[(size_t)(q * 4 + 3) * 64];
        }
#pragma unroll
        for (int q = 0; q < 8; ++q) {
            const int k = kbase + q;
            float* op = part + (((size_t)tg * Bc + b) * Kc + k) * Cc + ct * 128 + c32 * 4;
            *(float4*)op = acc[q];
        }
    }
}

// ---------------- finalize ----------------
__global__ __launch_bounds__(256) void k_finalize(const float* __restrict__ part, const float* __restrict__ asum,
        const float* __restrict__ centers, float* __restrict__ out) {
    __shared__ float invk[Kc];
    __shared__ float wss[4];
    __shared__ float ginv_s;
    const int b = blockIdx.x;
    const int wave = threadIdx.x >> 6, lane = threadIdx.x & 63;
    const size_t G = (size_t)Bc * Kc * Cc;
    float gss = 0.f;
    for (int k = wave; k < Kc; k += 4) {
        const float a = asum[b * Kc + k];
        const float* pp = part + ((size_t)b * Kc + k) * Cc;
        const float* cp = centers + (size_t)k * Cc;
        float ss = 0.f;
#pragma unroll
        for (int cpass = 0; cpass < 8; ++cpass) {
            int c = cpass * 64 + lane;
            float v = pp[c] + pp[c + G] + pp[c + 2 * G] + pp[c + 3 * G] - a * cp[c];
            ss += v * v;
        }
#pragma unroll
        for (int o = 1; o < 64; o <<= 1) ss += __shfl_xor(ss, o);
        float inv = 1.f / fmaxf(sqrtf(ss), 1e-12f);
        if (lane == 0) invk[k] = inv;
        gss += ss * inv * inv;
    }
    if (lane == 0) wss[wave] = gss;
    __syncthreads();
    if (threadIdx.x == 0) {
        float g = wss[0] + wss[1] + wss[2] + wss[3];
        ginv_s = 1.f / fmaxf(sqrtf(g), 1e-12f);
    }
    __syncthreads();
    const float gi = ginv_s;
    for (int k = wave; k < Kc; k += 4) {
        const float a = asum[b * Kc + k];
        const float* pp = part + ((size_t)b * Kc + k) * Cc;
        const float* cp = centers + (size_t)k * Cc;
        const float scl = invk[k] * gi;
        float* op = out + ((size_t)b * Kc + k) * Cc;
#pragma unroll
        for (int cpass = 0; cpass < 8; ++cpass) {
            int c = cpass * 64 + lane;
            float v = pp[c] + pp[c + G] + pp[c + 2 * G] + pp[c + 3 * G] - a * cp[c];
            op[c] = v * scl;
        }
    }
}

extern "C" void kernel_launch(void* const* d_in, const int* in_sizes, int n_in,
                              void* d_out, int out_size, void* d_ws, size_t ws_size,
                              hipStream_t stream) {
    (void)in_sizes; (void)n_in; (void)out_size; (void)ws_size;
    const float* x       = (const float*)d_in[0];
    const float* centers = (const float*)d_in[1];
    const float* share_w = (const float*)d_in[2];
    const float* share_b = (const float*)d_in[3];
    const float* Uz      = (const float*)d_in[4];
    const float* Ur      = (const float*)d_in[5];
    const float* Uh      = (const float*)d_in[6];
    float* out = (float*)d_out;
    float* ws  = (float*)d_ws;

    float* wxb    = ws;                      // [T][B][K][S], reused later as part
    float* part   = ws;                      // alias (wxb dead after GRU)
    float* assign = ws + (size_t)TBKS;       // [T][B][K][S]
    float* zb     = assign + (size_t)TBKS;   // [B][K][S]
    float* rh     = zb + (size_t)BKS;
    float* wt     = rh + (size_t)BKS;        // [C][K]
    float* asum   = wt + (size_t)Kc * Cc;    // [B][K]
    int*   cnt    = (int*)(asum + (size_t)Bc * Kc);  // 16 counters, 64B apart

    const size_t gru_lds = (size_t)(GP_TOT + 8 * 32 * 64) * 4;   // 136.1 KB
    const size_t ein_lds = (size_t)(196 * 68 + 28 * 132) * 4;    // 66.5 KB

    hipMemsetAsync(cnt, 0, 16 * 16 * sizeof(int), stream);
    k_transpose_w<<<dim3((Kc * Cc + 255) / 256), 256, 0, stream>>>(share_w, wt);
    k_conv1x1<<<dim3(392), 128, 0, stream>>>(x, wt, share_b, wxb);
    {
        void* args[] = {(void*)&wxb, (void*)&Uz, (void*)&Ur, (void*)&Uh,
                        (void*)&zb, (void*)&rh, (void*)&assign, (void*)&cnt};
        hipLaunchCooperativeKernel((const void*)k_gru_persist, dim3(256), dim3(512),
                                   args, (unsigned)gru_lds, stream);
    }
    k_asum<<<dim3(Bc * Kc), 64, 0, stream>>>(assign, asum);
    k_einsum<<<dim3(4, 4, Bc), 512, ein_lds, stream>>>(x, assign, part);
    k_finalize<<<dim3(Bc), 256, 0, stream>>>(part, asum, centers, out);
}

// Round 5
// 656.165 us; speedup vs baseline: 2.0424x; 2.0424x over previous
//
#include <hip/hip_runtime.h>

#define Bc 16
#define Tc 16
#define Cc 512
#define Kc 64
#define Sc 196
#define KS (Kc*Sc)          // 12544
#define BKS (Bc*Kc*Sc)      // 200704
#define TBKS (Tc*BKS)       // 3211264

#define GPLANE 288                    // 18 rows * 16 cols per plane
#define GP_TOT (16 + 64*GPLANE + 16)  // 18464 floats incl guards

__device__ __forceinline__ float sigmoid_f(float x) { return 1.f / (1.f + __expf(-x)); }
__device__ __forceinline__ float tanh_f(float x) { return 1.f - 2.f / (__expf(2.f * x) + 1.f); }

// ---------------- transpose share_w: wt[c][k] = w[k][c] ----------------
__global__ __launch_bounds__(256) void k_transpose_w(const float* __restrict__ w, float* __restrict__ wt) {
    int idx = blockIdx.x * 256 + threadIdx.x;
    if (idx < Kc * Cc) {
        int k = idx & 63, c = idx >> 6;
        wt[idx] = w[k * Cc + c];
    }
}

// ---------------- conv1x1: 256 thr, 64 gs/block, register-double-buffered staging ----------------
__global__ __launch_bounds__(256) void k_conv1x1(const float* __restrict__ x, const float* __restrict__ wt,
                                                 const float* __restrict__ bias, float* __restrict__ wxb) {
    __shared__ float Ws[32][64];
    __shared__ float Xs[32][64];
    const int tid = threadIdx.x;
    const int gs0 = blockIdx.x * 64;
    const int kt = tid >> 4;          // k = kt*4 + i
    const int sg = tid & 15;          // gs col = sg*4 + j
    const int go = tid & 63;          // staging column
    const int cpart = tid >> 6;       // staging row group (0..3)
    const int gs_c = gs0 + go;
    const int n_c = gs_c / Sc, s_c = gs_c - n_c * Sc;
    const float* xcol = x + (size_t)n_c * (Cc * Sc) + s_c;

    float xr[8], wr[8];
#pragma unroll
    for (int q = 0; q < 8; ++q) {
        int c = cpart * 8 + q;
        xr[q] = xcol[(size_t)c * Sc];
        wr[q] = wt[(size_t)c * 64 + go];
    }
    float acc[4][4] = {};
    for (int c0 = 0; c0 < Cc; c0 += 32) {
        __syncthreads();
#pragma unroll
        for (int q = 0; q < 8; ++q) {
            Xs[cpart * 8 + q][go] = xr[q];
            Ws[cpart * 8 + q][go] = wr[q];
        }
        __syncthreads();
        if (c0 + 32 < Cc) {
#pragma unroll
            for (int q = 0; q < 8; ++q) {
                int c = c0 + 32 + cpart * 8 + q;
                xr[q] = xcol[(size_t)c * Sc];
                wr[q] = wt[(size_t)c * 64 + go];
            }
        }
#pragma unroll
        for (int cc = 0; cc < 32; ++cc) {
            float4 wv = *(const float4*)&Ws[cc][kt * 4];
            float4 xv = *(const float4*)&Xs[cc][sg * 4];
            acc[0][0] += wv.x * xv.x; acc[0][1] += wv.x * xv.y; acc[0][2] += wv.x * xv.z; acc[0][3] += wv.x * xv.w;
            acc[1][0] += wv.y * xv.x; acc[1][1] += wv.y * xv.y; acc[1][2] += wv.y * xv.z; acc[1][3] += wv.y * xv.w;
            acc[2][0] += wv.z * xv.x; acc[2][1] += wv.z * xv.y; acc[2][2] += wv.z * xv.z; acc[2][3] += wv.z * xv.w;
            acc[3][0] += wv.w * xv.x; acc[3][1] += wv.w * xv.y; acc[3][2] += wv.w * xv.z; acc[3][3] += wv.w * xv.w;
        }
    }
#pragma unroll
    for (int i = 0; i < 4; ++i) {
        int k = kt * 4 + i;
        float bv = bias[k];
#pragma unroll
        for (int j = 0; j < 4; ++j) {
            int gs = gs0 + sg * 4 + j;
            int n = gs / Sc, s = gs - (gs / Sc) * Sc;
            int t = n & 15, b = n >> 4;
            wxb[(((size_t)t * Bc + b) * Kc + k) * Sc + s] = acc[i][j] + bv;
        }
    }
}

// ---------------- GRU gates: 1024 thr, 16 waves = (k-pair kp) x (ki-eighth kih) ----------------
// grid (16 b, 16 ktile). red = [2 kp][8 kih][16 v][64 lane], v = g*8 + r*4 + j
__global__ __launch_bounds__(1024) void k_gru_gates(const float* __restrict__ assign,
        const float* __restrict__ wxb, const float* __restrict__ Uz, const float* __restrict__ Ur,
        float* __restrict__ zb, float* __restrict__ rh, int t) {
    extern __shared__ float lds[];
    float* P = lds + 16;
    float* red = lds + GP_TOT;
    const int b = blockIdx.x;
    const int k0 = blockIdx.y * 4;
    const int tid = threadIdx.x;
    const float* wxb_t = wxb + (size_t)t * BKS;

    for (int i = tid; i < GP_TOT; i += 1024) lds[i] = 0.f;
    __syncthreads();
    if (t > 0) {
        const float* hb = assign + (size_t)(t - 1) * BKS + (size_t)b * KS;
        for (int i = tid; i < KS; i += 1024) {
            int kk = i / Sc, s = i - kk * Sc;
            int y = s / 14, xx = s - y * 14;
            P[kk * GPLANE + (y + 2) * 16 + xx + 1] = hb[i];
        }
    }
    __syncthreads();

    const int wv = __builtin_amdgcn_readfirstlane(tid >> 6);
    const int lane = tid & 63;
    const int kp = wv >> 3, kih = wv & 7;
    const int yp = lane >> 2, xq = (lane & 3) << 2;
    const float* uz0 = Uz + (size_t)(k0 + kp * 2) * 576 + kih * 72;
    const float* ur0 = Ur + (size_t)(k0 + kp * 2) * 576 + kih * 72;
    float az[2][4] = {}, ar[2][4] = {};
    const float* Pw = P + (size_t)(kih * 8) * GPLANE + yp * 16 + xq;
#pragma unroll 2
    for (int ki = 0; ki < 8; ++ki) {
        const float* pk = Pw + ki * GPLANE;
#pragma unroll
        for (int dy = 0; dy < 3; ++dy) {
            const float* row = pk + dy * 16;
            float4 m = *(const float4*)row;
            float e0 = row[-1], e4 = row[4];
#pragma unroll
            for (int r = 0; r < 2; ++r) {
                const float* wz = uz0 + r * 576 + ki * 9 + dy * 3;
                float c0 = wz[0], c1 = wz[1], c2 = wz[2];
                az[r][0] += c0*e0  + c1*m.x + c2*m.y;
                az[r][1] += c0*m.x + c1*m.y + c2*m.z;
                az[r][2] += c0*m.y + c1*m.z + c2*m.w;
                az[r][3] += c0*m.z + c1*m.w + c2*e4;
                const float* wr = ur0 + r * 576 + ki * 9 + dy * 3;
                float d0 = wr[0], d1 = wr[1], d2 = wr[2];
                ar[r][0] += d0*e0  + d1*m.x + d2*m.y;
                ar[r][1] += d0*m.x + d1*m.y + d2*m.z;
                ar[r][2] += d0*m.y + d1*m.z + d2*m.w;
                ar[r][3] += d0*m.z + d1*m.w + d2*e4;
            }
        }
    }
    {
        float* rp = red + (size_t)wv * (16 * 64) + lane;
#pragma unroll
        for (int r = 0; r < 2; ++r)
#pragma unroll
            for (int j = 0; j < 4; ++j) {
                rp[(size_t)(r * 4 + j) * 64] = az[r][j];
                rp[(size_t)(8 + r * 4 + j) * 64] = ar[r][j];
            }
    }
    __syncthreads();
    {
        const int yq = lane >> 2;
#pragma unroll
        for (int m = 0; m < 2; ++m) {
            const int o = wv * 2 + m;
            const int kp_o = o >> 4, v = o & 15;
            float s0 = 0.f;
#pragma unroll
            for (int w8 = 0; w8 < 8; ++w8)
                s0 += red[(size_t)((kp_o * 8 + w8) * 16 + v) * 64 + lane];
            const int g = v >> 3, r = (v >> 2) & 1, j = v & 3;
            const int k = k0 + kp_o * 2 + r;
            const int xb = ((lane & 3) << 2) + j;
            if (yq >= 1 && yq <= 14 && xb >= 1 && xb <= 14) {
                const int s = (yq - 1) * 14 + (xb - 1);
                const size_t base = ((size_t)b * Kc + k) * Sc + s;
                float pre = wxb_t[base];
                float sv = sigmoid_f(pre + s0);
                if (g == 0) {
                    zb[base] = sv;
                } else {
                    float hv = P[(size_t)k * GPLANE + (yq + 1) * 16 + xb];
                    rh[base] = sv * hv;
                }
            }
        }
    }
}

// ---------------- GRU out: 1024 thr; hh = tanh(wxb + conv(rh,Uh)); h = (1-z)*hh + z*hprev ----------------
// red = [2 kp][8 kih][8 v][64 lane], v = r*4 + j
__global__ __launch_bounds__(1024) void k_gru_out(const float* __restrict__ rhin,
        const float* __restrict__ wxb, const float* __restrict__ Uh, const float* __restrict__ zb,
        float* __restrict__ assign, int t) {
    extern __shared__ float lds[];
    float* P = lds + 16;
    float* red = lds + GP_TOT;
    const int b = blockIdx.x;
    const int k0 = blockIdx.y * 4;
    const int tid = threadIdx.x;
    const float* wxb_t = wxb + (size_t)t * BKS;

    for (int i = tid; i < GP_TOT; i += 1024) lds[i] = 0.f;
    __syncthreads();
    {
        const float* hb = rhin + (size_t)b * KS;
        for (int i = tid; i < KS; i += 1024) {
            int kk = i / Sc, s = i - kk * Sc;
            int y = s / 14, xx = s - y * 14;
            P[kk * GPLANE + (y + 2) * 16 + xx + 1] = hb[i];
        }
    }
    __syncthreads();

    const int wv = __builtin_amdgcn_readfirstlane(tid >> 6);
    const int lane = tid & 63;
    const int kp = wv >> 3, kih = wv & 7;
    const int yp = lane >> 2, xq = (lane & 3) << 2;
    const float* uh0 = Uh + (size_t)(k0 + kp * 2) * 576 + kih * 72;
    float ah[2][4] = {};
    const float* Pw = P + (size_t)(kih * 8) * GPLANE + yp * 16 + xq;
#pragma unroll 2
    for (int ki = 0; ki < 8; ++ki) {
        const float* pk = Pw + ki * GPLANE;
#pragma unroll
        for (int dy = 0; dy < 3; ++dy) {
            const float* row = pk + dy * 16;
            float4 m = *(const float4*)row;
            float e0 = row[-1], e4 = row[4];
#pragma unroll
            for (int r = 0; r < 2; ++r) {
                const float* wh = uh0 + r * 576 + ki * 9 + dy * 3;
                float c0 = wh[0], c1 = wh[1], c2 = wh[2];
                ah[r][0] += c0*e0  + c1*m.x + c2*m.y;
                ah[r][1] += c0*m.x + c1*m.y + c2*m.z;
                ah[r][2] += c0*m.y + c1*m.z + c2*m.w;
                ah[r][3] += c0*m.z + c1*m.w + c2*e4;
            }
        }
    }
    {
        float* rp = red + (size_t)wv * (8 * 64) + lane;
#pragma unroll
        for (int r = 0; r < 2; ++r)
#pragma unroll
            for (int j = 0; j < 4; ++j)
                rp[(size_t)(r * 4 + j) * 64] = ah[r][j];
    }
    __syncthreads();
    {
        const int yq = lane >> 2;
        const int o = wv;                      // 16 outputs: kp_o*8 + v
        const int kp_o = o >> 3, v = o & 7;
        float s0 = 0.f;
#pragma unroll
        for (int w8 = 0; w8 < 8; ++w8)
            s0 += red[(size_t)((kp_o * 8 + w8) * 8 + v) * 64 + lane];
        const int r = v >> 2, j = v & 3;
        const int k = k0 + kp_o * 2 + r;
        const int xb = ((lane & 3) << 2) + j;
        if (yq >= 1 && yq <= 14 && xb >= 1 && xb <= 14) {
            const int s = (yq - 1) * 14 + (xb - 1);
            const size_t base = ((size_t)b * Kc + k) * Sc + s;
            float pre = wxb_t[base];
            float zv = zb[base];
            float hp = (t > 0) ? assign[(size_t)(t - 1) * BKS + base] : 0.f;
            float hh = tanh_f(pre + s0);
            assign[(size_t)t * BKS + base] = (1.f - zv) * hh + zv * hp;
        }
    }
}

// ---------------- asum_tot[b][k] = sum_{t,s} assign ----------------
__global__ __launch_bounds__(64) void k_asum(const float* __restrict__ assign, float* __restrict__ asum) {
    const int bk = blockIdx.x;
    const int b = bk >> 6, k = bk & 63;
    float s = 0.f;
    for (int i = threadIdx.x; i < Tc * Sc; i += 64) {
        int t = i / Sc, sp = i - t * Sc;
        s += assign[(((size_t)t * Bc + b) * Kc + k) * Sc + sp];
    }
#pragma unroll
    for (int o = 1; o < 64; o <<= 1) s += __shfl_xor(s, o);
    if (threadIdx.x == 0) asum[bk] = s;
}

// ---------------- einsum: 512 thr, conflict-free Xs via register transpose, s-half split ----------------
__global__ __launch_bounds__(512) void k_einsum(const float* __restrict__ x, const float* __restrict__ assign,
                                                float* __restrict__ part) {
    extern __shared__ float lds[];
    float* As = lds;                 // [196][68]
    float* Xs = lds + 196 * 68;      // [28][132]
    const int ct = blockIdx.x, tg = blockIdx.y, b = blockIdx.z;
    const int tid = threadIdx.x;
    const int wave = tid >> 6, lane = tid & 63;
    const int kq = wave & 3, sh = wave >> 2;
    const int kh = lane >> 5, c32 = lane & 31;
    const int kbase = kq * 16 + kh * 8;
    float4 acc[8] = {};
    for (int ti = 0; ti < 4; ++ti) {
        const int t = tg * 4 + ti;
        const int n = b * Tc + t;
        __syncthreads();
        {
            const float* ap = assign + ((size_t)t * Bc + b) * (Kc * Sc);
            for (int i = tid; i < Kc * Sc; i += 512) {
                int kk = i / Sc, s = i - kk * Sc;
                As[(size_t)s * 68 + kk] = ap[i];
            }
        }
        for (int sc = 0; sc < 7; ++sc) {
            const int sb = sc * 28;
            __syncthreads();
            if (tid < 224) {
                const int sg = tid >> 5, cgi = tid & 31;
                const float* xp = x + ((size_t)n * Cc + ct * 128 + cgi * 4) * Sc + sb + sg * 4;
                float4 r0 = *(const float4*)xp;
                float4 r1 = *(const float4*)(xp + Sc);
                float4 r2 = *(const float4*)(xp + 2 * Sc);
                float4 r3 = *(const float4*)(xp + 3 * Sc);
                float* xd = Xs + (size_t)(sg * 4) * 132 + cgi * 4;
                *(float4*)(xd)       = make_float4(r0.x, r1.x, r2.x, r3.x);
                *(float4*)(xd + 132) = make_float4(r0.y, r1.y, r2.y, r3.y);
                *(float4*)(xd + 264) = make_float4(r0.z, r1.z, r2.z, r3.z);
                *(float4*)(xd + 396) = make_float4(r0.w, r1.w, r2.w, r3.w);
            }
            __syncthreads();
            const int s0 = sh * 14;
#pragma unroll 2
            for (int si = 0; si < 14; ++si) {
                const int sl = s0 + si;
                const float* ap = As + (size_t)(sb + sl) * 68 + kbase;
                float4 a0 = *(const float4*)ap;
                float4 a1 = *(const float4*)(ap + 4);
                float4 xv = *(const float4*)(Xs + (size_t)sl * 132 + c32 * 4);
                acc[0].x += a0.x * xv.x; acc[0].y += a0.x * xv.y; acc[0].z += a0.x * xv.z; acc[0].w += a0.x * xv.w;
                acc[1].x += a0.y * xv.x; acc[1].y += a0.y * xv.y; acc[1].z += a0.y * xv.z; acc[1].w += a0.y * xv.w;
                acc[2].x += a0.z * xv.x; acc[2].y += a0.z * xv.y; acc[2].z += a0.z * xv.z; acc[2].w += a0.z * xv.w;
                acc[3].x += a0.w * xv.x; acc[3].y += a0.w * xv.y; acc[3].z += a0.w * xv.z; acc[3].w += a0.w * xv.w;
                acc[4].x += a1.x * xv.x; acc[4].y += a1.x * xv.y; acc[4].z += a1.x * xv.z; acc[4].w += a1.x * xv.w;
                acc[5].x += a1.y * xv.x; acc[5].y += a1.y * xv.y; acc[5].z += a1.y * xv.z; acc[5].w += a1.y * xv.w;
                acc[6].x += a1.z * xv.x; acc[6].y += a1.z * xv.y; acc[6].z += a1.z * xv.z; acc[6].w += a1.z * xv.w;
                acc[7].x += a1.w * xv.x; acc[7].y += a1.w * xv.y; acc[7].z += a1.w * xv.z; acc[7].w += a1.w * xv.w;
            }
        }
    }
    __syncthreads();
    if (sh == 1) {
        float* rp = As + (size_t)kq * 2048 + lane;
#pragma unroll
        for (int q = 0; q < 8; ++q) {
            rp[(size_t)(q * 4 + 0) * 64] = acc[q].x;
            rp[(size_t)(q * 4 + 1) * 64] = acc[q].y;
            rp[(size_t)(q * 4 + 2) * 64] = acc[q].z;
            rp[(size_t)(q * 4 + 3) * 64] = acc[q].w;
        }
    }
    __syncthreads();
    if (sh == 0) {
        const float* rp = As + (size_t)kq * 2048 + lane;
#pragma unroll
        for (int q = 0; q < 8; ++q) {
            acc[q].x += rp[(size_t)(q * 4 + 0) * 64];
            acc[q].y += rp[(size_t)(q * 4 + 1) * 64];
            acc[q].z += rp[(size_t)(q * 4 + 2) * 64];
            acc[q].w += rp[(size_t)(q * 4 + 3) * 64];
        }
#pragma unroll
        for (int q = 0; q < 8; ++q) {
            const int k = kbase + q;
            float* op = part + (((size_t)tg * Bc + b) * Kc + k) * Cc + ct * 128 + c32 * 4;
            *(float4*)op = acc[q];
        }
    }
}

// ---------------- finalize ----------------
__global__ __launch_bounds__(256) void k_finalize(const float* __restrict__ part, const float* __restrict__ asum,
        const float* __restrict__ centers, float* __restrict__ out) {
    __shared__ float invk[Kc];
    __shared__ float wss[4];
    __shared__ float ginv_s;
    const int b = blockIdx.x;
    const int wave = threadIdx.x >> 6, lane = threadIdx.x & 63;
    const size_t G = (size_t)Bc * Kc * Cc;
    float gss = 0.f;
    for (int k = wave; k < Kc; k += 4) {
        const float a = asum[b * Kc + k];
        const float* pp = part + ((size_t)b * Kc + k) * Cc;
        const float* cp = centers + (size_t)k * Cc;
        float ss = 0.f;
#pragma unroll
        for (int cpass = 0; cpass < 8; ++cpass) {
            int c = cpass * 64 + lane;
            float v = pp[c] + pp[c + G] + pp[c + 2 * G] + pp[c + 3 * G] - a * cp[c];
            ss += v * v;
        }
#pragma unroll
        for (int o = 1; o < 64; o <<= 1) ss += __shfl_xor(ss, o);
        float inv = 1.f / fmaxf(sqrtf(ss), 1e-12f);
        if (lane == 0) invk[k] = inv;
        gss += ss * inv * inv;
    }
    if (lane == 0) wss[wave] = gss;
    __syncthreads();
    if (threadIdx.x == 0) {
        float g = wss[0] + wss[1] + wss[2] + wss[3];
        ginv_s = 1.f / fmaxf(sqrtf(g), 1e-12f);
    }
    __syncthreads();
    const float gi = ginv_s;
    for (int k = wave; k < Kc; k += 4) {
        const float a = asum[b * Kc + k];
        const float* pp = part + ((size_t)b * Kc + k) * Cc;
        const float* cp = centers + (size_t)k * Cc;
        const float scl = invk[k] * gi;
        float* op = out + ((size_t)b * Kc + k) * Cc;
#pragma unroll
        for (int cpass = 0; cpass < 8; ++cpass) {
            int c = cpass * 64 + lane;
            float v = pp[c] + pp[c + G] + pp[c + 2 * G] + pp[c + 3 * G] - a * cp[c];
            op[c] = v * scl;
        }
    }
}

extern "C" void kernel_launch(void* const* d_in, const int* in_sizes, int n_in,
                              void* d_out, int out_size, void* d_ws, size_t ws_size,
                              hipStream_t stream) {
    (void)in_sizes; (void)n_in; (void)out_size; (void)ws_size;
    const float* x       = (const float*)d_in[0];
    const float* centers = (const float*)d_in[1];
    const float* share_w = (const float*)d_in[2];
    const float* share_b = (const float*)d_in[3];
    const float* Uz      = (const float*)d_in[4];
    const float* Ur      = (const float*)d_in[5];
    const float* Uh      = (const float*)d_in[6];
    float* out = (float*)d_out;
    float* ws  = (float*)d_ws;

    float* wxb    = ws;                      // [T][B][K][S], reused later as part
    float* part   = ws;                      // alias (wxb dead after GRU)
    float* assign = ws + (size_t)TBKS;       // [T][B][K][S]
    float* zb     = assign + (size_t)TBKS;   // [B][K][S]
    float* rh     = zb + (size_t)BKS;
    float* wt     = rh + (size_t)BKS;        // [C][K]
    float* asum   = wt + (size_t)Kc * Cc;    // [B][K]

    const size_t gates_lds = (size_t)(GP_TOT + 16 * 16 * 64) * 4;  // 139.4 KB
    const size_t outk_lds  = (size_t)(GP_TOT + 16 * 8 * 64) * 4;   // 106.6 KB
    const size_t ein_lds   = (size_t)(196 * 68 + 28 * 132) * 4;    // 66.5 KB

    k_transpose_w<<<dim3((Kc * Cc + 255) / 256), 256, 0, stream>>>(share_w, wt);
    k_conv1x1<<<dim3(784), 256, 0, stream>>>(x, wt, share_b, wxb);
    for (int t = 0; t < Tc; ++t) {
        k_gru_gates<<<dim3(16, 16), 1024, gates_lds, stream>>>(assign, wxb, Uz, Ur, zb, rh, t);
        k_gru_out<<<dim3(16, 16), 1024, outk_lds, stream>>>(rh, wxb, Uh, zb, assign, t);
    }
    k_asum<<<dim3(Bc * Kc), 64, 0, stream>>>(assign, asum);
    k_einsum<<<dim3(4, 4, Bc), 512, ein_lds, stream>>>(x, assign, part);
    k_finalize<<<dim3(Bc), 256, 0, stream>>>(part, asum, centers, out);
}